// Round 1
// baseline (347.909 us; speedup 1.0000x reference)
//
#include <hip/hip_runtime.h>
#include <hip/hip_bf16.h>

#define N_ROWS 32768
#define K_DIM 512
#define OUT_DIM 512
#define N_TYPES 8

#define BM 128
#define BN 128
#define BK 32

typedef __attribute__((ext_vector_type(8))) short bf16x8;
typedef __attribute__((ext_vector_type(4))) float f32x4;

__device__ inline ushort f2bf(float f) {
    __hip_bfloat16 h = __float2bfloat16(f);
    return *reinterpret_cast<ushort*>(&h);
}

// meta layout (ints): [0..7] counts, [8..15] bases, [16..23] cursors
__global__ void k_init(int* meta) {
    if (threadIdx.x < 24) meta[threadIdx.x] = 0;
}

__global__ void k_hist(const int* __restrict__ x_type, int* meta) {
    int i = blockIdx.x * 256 + threadIdx.x;
    if (i < N_ROWS) atomicAdd(&meta[x_type[i]], 1);
}

__global__ void k_scan(int* meta) {
    if (threadIdx.x == 0) {
        int s = 0;
        for (int t = 0; t < N_TYPES; ++t) { meta[8 + t] = s; s += meta[t]; }
    }
}

__global__ void k_fill(const int* __restrict__ x_type, int* meta, int* __restrict__ row_ids) {
    int i = blockIdx.x * 256 + threadIdx.x;
    if (i < N_ROWS) {
        int t = x_type[i];
        int pos = atomicAdd(&meta[16 + t], 1);
        row_ids[meta[8 + t] + pos] = i;
    }
}

// W[t][k][c] fp32 -> Wt[t][c][k] bf16   (64x64 tiles through LDS)
__global__ void k_wt(const float* __restrict__ W, ushort* __restrict__ Wt) {
    __shared__ float tile[64][65];
    int t = blockIdx.x, kb = blockIdx.y, cb = blockIdx.z;
    const float* src = W + (size_t)t * K_DIM * OUT_DIM + (size_t)kb * 64 * OUT_DIM + cb * 64;
    #pragma unroll
    for (int j = 0; j < 16; ++j) {
        int idx = threadIdx.x + j * 256;
        int r = idx >> 6, c = idx & 63;
        tile[r][c] = src[(size_t)r * OUT_DIM + c];
    }
    __syncthreads();
    ushort* dst = Wt + (size_t)t * OUT_DIM * K_DIM + (size_t)(cb * 64) * K_DIM + kb * 64;
    #pragma unroll
    for (int j = 0; j < 16; ++j) {
        int idx = threadIdx.x + j * 256;
        int cc = idx >> 6, kk = idx & 63;
        dst[(size_t)cc * K_DIM + kk] = f2bf(tile[kk][cc]);
    }
}

__global__ __launch_bounds__(256) void k_gemm(
    const float* __restrict__ x, const ushort* __restrict__ Wt,
    const int* __restrict__ meta, const int* __restrict__ row_ids,
    float* __restrict__ out) {

    __shared__ ushort As[BM][BK];   // x tile, bf16, [row][k]
    __shared__ ushort Bs[BN][BK];   // W tile transposed: [col][k]
    __shared__ int rids[BM];

    // map blockIdx.x -> (type, row-tile)
    int b = blockIdx.x;
    int type = -1, mt = 0, acc_tiles = 0;
    for (int t = 0; t < N_TYPES; ++t) {
        int cnt_t = meta[t];
        int nt = (cnt_t + BM - 1) / BM;
        if (b < acc_tiles + nt) { type = t; mt = b - acc_tiles; break; }
        acc_tiles += nt;
    }
    if (type < 0) return;

    int cnt  = meta[type];
    int base = meta[8 + type];
    int row0 = mt * BM;
    int nrows = min(BM, cnt - row0);

    int tid = threadIdx.x;
    if (tid < BM) rids[tid] = (tid < nrows) ? row_ids[base + row0 + tid] : -1;
    __syncthreads();

    int c0 = blockIdx.y * BN;
    const ushort* Wtt = Wt + (size_t)type * OUT_DIM * K_DIM + (size_t)c0 * K_DIM;

    f32x4 acc[4][4] = {};

    int wave = tid >> 6, lane = tid & 63;
    int wr = (wave >> 1) * 64;      // wave row base in tile
    int wc = (wave & 1) * 64;       // wave col base in tile
    int lrow = lane & 15;           // fragment row/col within 16
    int lk = (lane >> 4) * 8;       // fragment k offset

    // staging roles (fixed per thread)
    int sa_r = tid >> 1;            // A: row, 2 threads/row
    int sa_h = (tid & 1) * 16;      // A: 16-element half
    long sa_rid;
    {
        // re-read rid per iteration from shared instead (rids loaded above)
    }

    for (int kk = 0; kk < K_DIM; kk += BK) {
        // ---- stage A: fp32 -> bf16, 16 elems/thread ----
        {
            int rid = rids[sa_r];
            ushort tmp[16];
            if (rid >= 0) {
                const float* src = x + (size_t)rid * K_DIM + kk + sa_h;
                #pragma unroll
                for (int j = 0; j < 16; j += 4) {
                    float4 v = *reinterpret_cast<const float4*>(src + j);
                    tmp[j + 0] = f2bf(v.x);
                    tmp[j + 1] = f2bf(v.y);
                    tmp[j + 2] = f2bf(v.z);
                    tmp[j + 3] = f2bf(v.w);
                }
            } else {
                #pragma unroll
                for (int j = 0; j < 16; ++j) tmp[j] = 0;
            }
            *reinterpret_cast<uint4*>(&As[sa_r][sa_h])     = *reinterpret_cast<uint4*>(&tmp[0]);
            *reinterpret_cast<uint4*>(&As[sa_r][sa_h + 8]) = *reinterpret_cast<uint4*>(&tmp[8]);
        }
        // ---- stage B: bf16 copy, 16 elems/thread ----
        {
            int c = tid >> 1;
            int h = (tid & 1) * 16;
            const ushort* src = Wtt + (size_t)c * K_DIM + kk + h;
            *reinterpret_cast<uint4*>(&Bs[c][h])     = *reinterpret_cast<const uint4*>(src);
            *reinterpret_cast<uint4*>(&Bs[c][h + 8]) = *reinterpret_cast<const uint4*>(src + 8);
        }
        __syncthreads();

        bf16x8 af[4], bfr[4];
        #pragma unroll
        for (int mi = 0; mi < 4; ++mi)
            af[mi] = *reinterpret_cast<const bf16x8*>(&As[wr + mi * 16 + lrow][lk]);
        #pragma unroll
        for (int ni = 0; ni < 4; ++ni)
            bfr[ni] = *reinterpret_cast<const bf16x8*>(&Bs[wc + ni * 16 + lrow][lk]);
        #pragma unroll
        for (int mi = 0; mi < 4; ++mi)
            #pragma unroll
            for (int ni = 0; ni < 4; ++ni)
                acc[mi][ni] = __builtin_amdgcn_mfma_f32_16x16x32_bf16(af[mi], bfr[ni], acc[mi][ni], 0, 0, 0);
        __syncthreads();
    }

    // epilogue: D row = (lane>>4)*4 + rr, col = lane&15   [guide §3, m89/m91]
    int rgrp = (lane >> 4) * 4;
    #pragma unroll
    for (int mi = 0; mi < 4; ++mi) {
        #pragma unroll
        for (int rr = 0; rr < 4; ++rr) {
            int lr = wr + mi * 16 + rgrp + rr;
            int gr = rids[lr];
            if (gr >= 0) {
                float* dst = out + (size_t)gr * OUT_DIM + c0 + wc;
                #pragma unroll
                for (int ni = 0; ni < 4; ++ni)
                    dst[ni * 16 + lrow] = acc[mi][ni][rr];
            }
        }
    }
}

extern "C" void kernel_launch(void* const* d_in, const int* in_sizes, int n_in,
                              void* d_out, int out_size, void* d_ws, size_t ws_size,
                              hipStream_t stream) {
    const float* x      = (const float*)d_in[0];
    const int*   x_type = (const int*)d_in[1];
    const float* W      = (const float*)d_in[2];
    float* out          = (float*)d_out;

    // workspace layout
    char* ws = (char*)d_ws;
    int* meta      = (int*)ws;                       // 24 ints
    int* row_ids   = (int*)(ws + 256);               // N ints = 128 KB
    ushort* Wt     = (ushort*)(ws + 256 + sizeof(int) * N_ROWS);  // 4 MB bf16

    k_init<<<1, 64, 0, stream>>>(meta);
    k_hist<<<N_ROWS / 256, 256, 0, stream>>>(x_type, meta);
    k_scan<<<1, 64, 0, stream>>>(meta);
    k_fill<<<N_ROWS / 256, 256, 0, stream>>>(x_type, meta, row_ids);

    dim3 wgrid(N_TYPES, K_DIM / 64, OUT_DIM / 64);
    k_wt<<<wgrid, 256, 0, stream>>>(W, Wt);

    // max row tiles = N/BM + (T-1) padding tiles; one extra type-worth margin
    dim3 ggrid(N_ROWS / BM + N_TYPES, OUT_DIM / BN);
    k_gemm<<<ggrid, 256, 0, stream>>>(x, Wt, meta, row_ids, out);
}

// Round 2
// 72.725 us; speedup vs baseline: 4.7839x; 4.7839x over previous
//
#include <hip/hip_runtime.h>
#include <hip/hip_bf16.h>

#define N_ROWS 32768
#define K_DIM 512
#define OUT_DIM 512
#define N_TYPES 8

#define BM 128
#define BN 128
#define BK 32

typedef __attribute__((ext_vector_type(8))) short bf16x8;
typedef __attribute__((ext_vector_type(4))) float f32x4;

__device__ inline ushort f2bf(float f) {
    __hip_bfloat16 h = __float2bfloat16(f);
    return *reinterpret_cast<ushort*>(&h);
}

// meta layout (ints): [0..7] counts, [8..15] bases, [16..23] cursors
__global__ void k_init(int* meta) {
    if (threadIdx.x < 24) meta[threadIdx.x] = 0;
}

// per-block LDS histogram -> 8 global atomics per block
__global__ void k_hist(const int* __restrict__ x_type, int* meta) {
    __shared__ int cnt[N_TYPES];
    if (threadIdx.x < N_TYPES) cnt[threadIdx.x] = 0;
    __syncthreads();
    int i = blockIdx.x * 256 + threadIdx.x;
    atomicAdd(&cnt[x_type[i]], 1);
    __syncthreads();
    if (threadIdx.x < N_TYPES && cnt[threadIdx.x] > 0)
        atomicAdd(&meta[threadIdx.x], cnt[threadIdx.x]);
}

__global__ void k_scan(int* meta) {
    if (threadIdx.x == 0) {
        int s = 0;
        for (int t = 0; t < N_TYPES; ++t) {
            meta[8 + t] = s;          // base
            meta[16 + t] = s;         // absolute cursor
            s += meta[t];
        }
    }
}

// per-block LDS hist -> reserve range with 8 global atomics -> scatter
__global__ void k_fill(const int* __restrict__ x_type, int* meta, int* __restrict__ row_ids) {
    __shared__ int lcnt[N_TYPES];
    __shared__ int lbase[N_TYPES];
    if (threadIdx.x < N_TYPES) lcnt[threadIdx.x] = 0;
    __syncthreads();
    int i = blockIdx.x * 256 + threadIdx.x;
    int t = x_type[i];
    int lpos = atomicAdd(&lcnt[t], 1);
    __syncthreads();
    if (threadIdx.x < N_TYPES)
        lbase[threadIdx.x] = (lcnt[threadIdx.x] > 0)
            ? atomicAdd(&meta[16 + threadIdx.x], lcnt[threadIdx.x]) : 0;
    __syncthreads();
    row_ids[lbase[t] + lpos] = i;
}

// W[t][k][c] fp32 -> Wt[t][c][k] bf16   (64x64 tiles through LDS)
__global__ void k_wt(const float* __restrict__ W, ushort* __restrict__ Wt) {
    __shared__ float tile[64][65];
    int t = blockIdx.x, kb = blockIdx.y, cb = blockIdx.z;
    const float* src = W + (size_t)t * K_DIM * OUT_DIM + (size_t)kb * 64 * OUT_DIM + cb * 64;
    #pragma unroll
    for (int j = 0; j < 16; ++j) {
        int idx = threadIdx.x + j * 256;
        int r = idx >> 6, c = idx & 63;
        tile[r][c] = src[(size_t)r * OUT_DIM + c];
    }
    __syncthreads();
    ushort* dst = Wt + (size_t)t * OUT_DIM * K_DIM + (size_t)(cb * 64) * K_DIM + kb * 64;
    #pragma unroll
    for (int j = 0; j < 16; ++j) {
        int idx = threadIdx.x + j * 256;
        int cc = idx >> 6, kk = idx & 63;
        dst[(size_t)cc * K_DIM + kk] = f2bf(tile[kk][cc]);
    }
}

__global__ __launch_bounds__(256) void k_gemm(
    const float* __restrict__ x, const ushort* __restrict__ Wt,
    const int* __restrict__ meta, const int* __restrict__ row_ids,
    float* __restrict__ out) {

    __shared__ ushort As[BM][BK];   // x tile, bf16, [row][k]
    __shared__ ushort Bs[BN][BK];   // W tile transposed: [col][k]
    __shared__ int rids[BM];

    // map blockIdx.x -> (type, row-tile)
    int b = blockIdx.x;
    int type = -1, mt = 0, acc_tiles = 0;
    for (int t = 0; t < N_TYPES; ++t) {
        int cnt_t = meta[t];
        int nt = (cnt_t + BM - 1) / BM;
        if (b < acc_tiles + nt) { type = t; mt = b - acc_tiles; break; }
        acc_tiles += nt;
    }
    if (type < 0) return;

    int cnt  = meta[type];
    int base = meta[8 + type];
    int row0 = mt * BM;
    int nrows = min(BM, cnt - row0);

    int tid = threadIdx.x;
    if (tid < BM) rids[tid] = (tid < nrows) ? row_ids[base + row0 + tid] : -1;
    __syncthreads();

    int c0 = blockIdx.y * BN;
    const ushort* Wtt = Wt + (size_t)type * OUT_DIM * K_DIM + (size_t)c0 * K_DIM;

    f32x4 acc[4][4] = {};

    int wave = tid >> 6, lane = tid & 63;
    int wr = (wave >> 1) * 64;      // wave row base in tile
    int wc = (wave & 1) * 64;       // wave col base in tile
    int lrow = lane & 15;           // fragment row/col within 16
    int lk = (lane >> 4) * 8;       // fragment k offset

    int sa_r = tid >> 1;            // A: row, 2 threads/row
    int sa_h = (tid & 1) * 16;      // A: 16-element half

    for (int kk = 0; kk < K_DIM; kk += BK) {
        // ---- stage A: fp32 -> bf16, 16 elems/thread ----
        {
            int rid = rids[sa_r];
            ushort tmp[16];
            if (rid >= 0) {
                const float* src = x + (size_t)rid * K_DIM + kk + sa_h;
                #pragma unroll
                for (int j = 0; j < 16; j += 4) {
                    float4 v = *reinterpret_cast<const float4*>(src + j);
                    tmp[j + 0] = f2bf(v.x);
                    tmp[j + 1] = f2bf(v.y);
                    tmp[j + 2] = f2bf(v.z);
                    tmp[j + 3] = f2bf(v.w);
                }
            } else {
                #pragma unroll
                for (int j = 0; j < 16; ++j) tmp[j] = 0;
            }
            *reinterpret_cast<uint4*>(&As[sa_r][sa_h])     = *reinterpret_cast<uint4*>(&tmp[0]);
            *reinterpret_cast<uint4*>(&As[sa_r][sa_h + 8]) = *reinterpret_cast<uint4*>(&tmp[8]);
        }
        // ---- stage B: bf16 copy, 16 elems/thread ----
        {
            int c = tid >> 1;
            int h = (tid & 1) * 16;
            const ushort* src = Wtt + (size_t)c * K_DIM + kk + h;
            *reinterpret_cast<uint4*>(&Bs[c][h])     = *reinterpret_cast<const uint4*>(src);
            *reinterpret_cast<uint4*>(&Bs[c][h + 8]) = *reinterpret_cast<const uint4*>(src + 8);
        }
        __syncthreads();

        bf16x8 af[4], bfr[4];
        #pragma unroll
        for (int mi = 0; mi < 4; ++mi)
            af[mi] = *reinterpret_cast<const bf16x8*>(&As[wr + mi * 16 + lrow][lk]);
        #pragma unroll
        for (int ni = 0; ni < 4; ++ni)
            bfr[ni] = *reinterpret_cast<const bf16x8*>(&Bs[wc + ni * 16 + lrow][lk]);
        #pragma unroll
        for (int mi = 0; mi < 4; ++mi)
            #pragma unroll
            for (int ni = 0; ni < 4; ++ni)
                acc[mi][ni] = __builtin_amdgcn_mfma_f32_16x16x32_bf16(af[mi], bfr[ni], acc[mi][ni], 0, 0, 0);
        __syncthreads();
    }

    // epilogue: D row = (lane>>4)*4 + rr, col = lane&15   [guide §3, m89/m91]
    int rgrp = (lane >> 4) * 4;
    #pragma unroll
    for (int mi = 0; mi < 4; ++mi) {
        #pragma unroll
        for (int rr = 0; rr < 4; ++rr) {
            int lr = wr + mi * 16 + rgrp + rr;
            int gr = rids[lr];
            if (gr >= 0) {
                float* dst = out + (size_t)gr * OUT_DIM + c0 + wc;
                #pragma unroll
                for (int ni = 0; ni < 4; ++ni)
                    dst[ni * 16 + lrow] = acc[mi][ni][rr];
            }
        }
    }
}

extern "C" void kernel_launch(void* const* d_in, const int* in_sizes, int n_in,
                              void* d_out, int out_size, void* d_ws, size_t ws_size,
                              hipStream_t stream) {
    const float* x      = (const float*)d_in[0];
    const int*   x_type = (const int*)d_in[1];
    const float* W      = (const float*)d_in[2];
    float* out          = (float*)d_out;

    // workspace layout
    char* ws = (char*)d_ws;
    int* meta      = (int*)ws;                       // 24 ints
    int* row_ids   = (int*)(ws + 256);               // N ints = 128 KB
    ushort* Wt     = (ushort*)(ws + 256 + sizeof(int) * N_ROWS);  // 4 MB bf16

    k_init<<<1, 64, 0, stream>>>(meta);
    k_hist<<<N_ROWS / 256, 256, 0, stream>>>(x_type, meta);
    k_scan<<<1, 64, 0, stream>>>(meta);
    k_fill<<<N_ROWS / 256, 256, 0, stream>>>(x_type, meta, row_ids);

    dim3 wgrid(N_TYPES, K_DIM / 64, OUT_DIM / 64);
    k_wt<<<wgrid, 256, 0, stream>>>(W, Wt);

    // max row tiles = N/BM + (T-1) padding tiles
    dim3 ggrid(N_ROWS / BM + N_TYPES, OUT_DIM / BN);
    k_gemm<<<ggrid, 256, 0, stream>>>(x, Wt, meta, row_ids, out);
}